// Round 1
// baseline (202.682 us; speedup 1.0000x reference)
//
#include <hip/hip_runtime.h>

#define NB 128
#define NA 64
#define NH1 256
#define NH2 256

// ws layout (floats):
//   SIM  [B][64][64]   @ 0        (524288)
//   SIMT [B][64][64]   @ 524288
//   WUU  [B][256][64]  @ 1048576  (2097152)
//   WII  [B][256][64]  @ 3145728
// total 5242880 floats = 20 MB

// K1: OUT[b][k][a] = sum_h W[k][h] * X[b][a][h]
// grid (4 kb, B, 2 side), block 256. lane = k (64 k's), q = t>>6 -> 16 a's each.
__global__ __launch_bounds__(256) void proj_kernel(
    const float* __restrict__ U, const float* __restrict__ I,
    const float* __restrict__ Wu, const float* __restrict__ Wi,
    float* __restrict__ WUU, float* __restrict__ WII)
{
    const int t    = threadIdx.x;
    const int kb   = blockIdx.x;   // 0..3
    const int b    = blockIdx.y;   // 0..127
    const int side = blockIdx.z;   // 0 user, 1 item
    const float* W = side ? Wi : Wu;
    const float* X = side ? I  : U;
    float* OUT     = side ? WII : WUU;

    const int k = kb * 64 + (t & 63);
    const int q = __builtin_amdgcn_readfirstlane(t >> 6); // wave-uniform 0..3

    float acc[16];
    #pragma unroll
    for (int aa = 0; aa < 16; ++aa) acc[aa] = 0.f;

    for (int hc = 0; hc < 4; ++hc) {   // h chunks of 64
        const int h0 = hc * 64;
        float4 wreg[16];
        const float4* wp = reinterpret_cast<const float4*>(W + (size_t)k * NH1 + h0);
        #pragma unroll
        for (int j = 0; j < 16; ++j) wreg[j] = wp[j];

        #pragma unroll
        for (int aa = 0; aa < 16; ++aa) {
            // wave-uniform address -> scalar loads
            const float4* xp = reinterpret_cast<const float4*>(
                X + ((size_t)b * NA + (q * 16 + aa)) * NH1 + h0);
            float s0 = 0.f, s1 = 0.f, s2 = 0.f, s3 = 0.f;
            #pragma unroll
            for (int j = 0; j < 16; ++j) {
                float4 xv = xp[j];
                s0 = fmaf(wreg[j].x, xv.x, s0);
                s1 = fmaf(wreg[j].y, xv.y, s1);
                s2 = fmaf(wreg[j].z, xv.z, s2);
                s3 = fmaf(wreg[j].w, xv.w, s3);
            }
            acc[aa] += (s0 + s1) + (s2 + s3);
        }
    }

    float* op = OUT + ((size_t)b * NH2 + k) * NA + q * 16;
    #pragma unroll
    for (int aa = 0; aa < 16; aa += 4) {
        float4 v = make_float4(acc[aa], acc[aa + 1], acc[aa + 2], acc[aa + 3]);
        *reinterpret_cast<float4*>(op + aa) = v;
    }
}

// K2: sim[b][u][i] = 1/(1 + sum_h |U[b][u][h]-I[b][i][h]|); also writes sim^T.
// grid B, block 256 (16x16), 4x4 register tile per thread.
__global__ __launch_bounds__(256) void sim_kernel(
    const float* __restrict__ U, const float* __restrict__ I,
    float* __restrict__ SIM, float* __restrict__ SIMT)
{
    const int t  = threadIdx.x;
    const int b  = blockIdx.x;
    const int tx = t & 15, ty = t >> 4;
    const float4* U4 = reinterpret_cast<const float4*>(U + (size_t)b * NA * NH1);
    const float4* I4 = reinterpret_cast<const float4*>(I + (size_t)b * NA * NH1);

    float acc[4][4];
    #pragma unroll
    for (int du = 0; du < 4; ++du)
        #pragma unroll
        for (int di = 0; di < 4; ++di) acc[du][di] = 0.f;

    for (int h4 = 0; h4 < 64; ++h4) {
        float4 uv[4], iv[4];
        #pragma unroll
        for (int d = 0; d < 4; ++d) uv[d] = U4[(size_t)(4 * ty + d) * 64 + h4];
        #pragma unroll
        for (int d = 0; d < 4; ++d) iv[d] = I4[(size_t)(4 * tx + d) * 64 + h4];
        #pragma unroll
        for (int du = 0; du < 4; ++du)
            #pragma unroll
            for (int di = 0; di < 4; ++di) {
                acc[du][di] += fabsf(uv[du].x - iv[di].x) + fabsf(uv[du].y - iv[di].y)
                             + fabsf(uv[du].z - iv[di].z) + fabsf(uv[du].w - iv[di].w);
            }
    }
    #pragma unroll
    for (int du = 0; du < 4; ++du)
        #pragma unroll
        for (int di = 0; di < 4; ++di)
            acc[du][di] = 1.0f / (1.0f + acc[du][di]);

    float* SB = SIM  + (size_t)b * NA * NA;
    float* TB = SIMT + (size_t)b * NA * NA;
    #pragma unroll
    for (int du = 0; du < 4; ++du) {
        float4 v = make_float4(acc[du][0], acc[du][1], acc[du][2], acc[du][3]);
        *reinterpret_cast<float4*>(SB + (size_t)(4 * ty + du) * NA + 4 * tx) = v;
    }
    #pragma unroll
    for (int di = 0; di < 4; ++di) {
        float4 v = make_float4(acc[0][di], acc[1][di], acc[2][di], acc[3][di]);
        *reinterpret_cast<float4*>(TB + (size_t)(4 * tx + di) * NA + 4 * ty) = v;
    }
}

// K3: scores + softmax. grid (B, 2 side), block 256.
// side 0 (user): score[u] = sum_k w_hu[k]*relu(WUU[b][k][u] + sum_i WII[b][k][i]*SIM[b][u][i])
// side 1 (item): score[i] = sum_k w_hi[k]*relu(WII[b][k][i] + sum_u WUU[b][k][u]*SIMT[b][i][u])
__global__ __launch_bounds__(256) void score_kernel(
    const float* __restrict__ WUU, const float* __restrict__ WII,
    const float* __restrict__ SIM, const float* __restrict__ SIMT,
    const float* __restrict__ w_hu, const float* __restrict__ w_hi,
    float* __restrict__ out)
{
    const int t    = threadIdx.x;
    const int b    = blockIdx.x;
    const int side = blockIdx.y;
    const float* ROWS  = side ? WUU : WII;   // dotted rows [b][k][0..63]
    const float* BIASM = side ? WII : WUU;
    const float* SM    = side ? SIMT : SIM;  // [b][own][other]
    const float* wv    = side ? w_hi : w_hu;

    const int own = t & 63;
    const int kq  = __builtin_amdgcn_readfirstlane(t >> 6); // 0..3

    float4 srow[16];
    const float4* sp = reinterpret_cast<const float4*>(SM + ((size_t)b * NA + own) * NA);
    #pragma unroll
    for (int j = 0; j < 16; ++j) srow[j] = sp[j];

    float partial = 0.f;
    for (int kk = 0; kk < 64; ++kk) {
        const int k = kq * 64 + kk;
        const float4* rp = reinterpret_cast<const float4*>(ROWS + ((size_t)b * NH2 + k) * NA);
        float s0 = 0.f, s1 = 0.f, s2 = 0.f, s3 = 0.f;
        #pragma unroll
        for (int j = 0; j < 16; ++j) {
            float4 rv = rp[j];
            s0 = fmaf(rv.x, srow[j].x, s0);
            s1 = fmaf(rv.y, srow[j].y, s1);
            s2 = fmaf(rv.z, srow[j].z, s2);
            s3 = fmaf(rv.w, srow[j].w, s3);
        }
        const float dot  = (s0 + s1) + (s2 + s3);
        const float bias = BIASM[((size_t)b * NH2 + k) * NA + own];
        const float h    = fmaxf(bias + dot, 0.f);
        partial = fmaf(wv[k], h, partial);
    }

    __shared__ float red[4][64];
    red[kq][own] = partial;
    __syncthreads();
    if (t < 64) {
        float sc = red[0][t] + red[1][t] + red[2][t] + red[3][t];
        float m = sc;
        #pragma unroll
        for (int off = 32; off >= 1; off >>= 1) m = fmaxf(m, __shfl_xor(m, off, 64));
        float e = __expf(sc - m);
        float ssum = e;
        #pragma unroll
        for (int off = 32; off >= 1; off >>= 1) ssum += __shfl_xor(ssum, off, 64);
        out[(size_t)side * (NB * NA) + (size_t)b * NA + t] = e / ssum;
    }
}

extern "C" void kernel_launch(void* const* d_in, const int* in_sizes, int n_in,
                              void* d_out, int out_size, void* d_ws, size_t ws_size,
                              hipStream_t stream)
{
    const float* U   = (const float*)d_in[0];
    const float* I   = (const float*)d_in[1];
    const float* Wu  = (const float*)d_in[2];
    const float* Wi  = (const float*)d_in[3];
    const float* whu = (const float*)d_in[4];
    const float* whi = (const float*)d_in[5];
    float* out = (float*)d_out;

    float* ws   = (float*)d_ws;
    float* SIM  = ws;
    float* SIMT = ws + 524288;
    float* WUU  = ws + 1048576;
    float* WII  = ws + 3145728;

    proj_kernel<<<dim3(4, NB, 2), 256, 0, stream>>>(U, I, Wu, Wi, WUU, WII);
    sim_kernel<<<dim3(NB), 256, 0, stream>>>(U, I, SIM, SIMT);
    score_kernel<<<dim3(NB, 2), 256, 0, stream>>>(WUU, WII, SIM, SIMT, whu, whi, out);
}

// Round 2
// 128.407 us; speedup vs baseline: 1.5784x; 1.5784x over previous
//
#include <hip/hip_runtime.h>

#define NB 128
#define NA 64
#define NH1 256
#define NH2 256

typedef __attribute__((ext_vector_type(8))) short bf16x8;
typedef __attribute__((ext_vector_type(4))) float f32x4;
typedef __attribute__((ext_vector_type(8))) unsigned short u16x8;
typedef __attribute__((ext_vector_type(4))) unsigned short u16x4;

__device__ __forceinline__ unsigned short f2bf(float f) {
    union { float f; unsigned u; } v; v.f = f;
    unsigned r = v.u + 0x7FFFu + ((v.u >> 16) & 1u);   // RNE, inputs are finite
    return (unsigned short)(r >> 16);
}
__device__ __forceinline__ float bf2f(unsigned short h) {
    union { unsigned u; float f; } v; v.u = ((unsigned)h) << 16;
    return v.f;
}

// ---------------- K0: f32 -> bf16 conversion of U, I, W_u, W_i ----------------
// 4,325,376 elems / 8 per thread / 256 per block = 2112 blocks exactly.
__global__ __launch_bounds__(256) void cvt_kernel(
    const float* __restrict__ U, const float* __restrict__ I,
    const float* __restrict__ Wu, const float* __restrict__ Wi,
    unsigned short* __restrict__ Ub, unsigned short* __restrict__ Ib,
    unsigned short* __restrict__ Wub, unsigned short* __restrict__ Wib)
{
    const size_t e = ((size_t)blockIdx.x * 256 + threadIdx.x) * 8;
    const size_t NU = (size_t)NB * NA * NH1;   // 2,097,152
    const size_t NW = (size_t)NH2 * NH1;       // 65,536
    const float* src; unsigned short* dst; size_t off;
    if (e < NU)               { src = U;  dst = Ub;  off = e; }
    else if (e < 2 * NU)      { src = I;  dst = Ib;  off = e - NU; }
    else if (e < 2 * NU + NW) { src = Wu; dst = Wub; off = e - 2 * NU; }
    else                      { src = Wi; dst = Wib; off = e - 2 * NU - NW; }
    float4 a = *reinterpret_cast<const float4*>(src + off);
    float4 b = *reinterpret_cast<const float4*>(src + off + 4);
    u16x8 o;
    o[0] = f2bf(a.x); o[1] = f2bf(a.y); o[2] = f2bf(a.z); o[3] = f2bf(a.w);
    o[4] = f2bf(b.x); o[5] = f2bf(b.y); o[6] = f2bf(b.z); o[7] = f2bf(b.w);
    *reinterpret_cast<u16x8*>(dst + off) = o;
}

// ---------------- K1: proj via MFMA. OUT[b][k][a] = sum_h W[k][h]*X[b][a][h] --
// grid (B, side), 512 thr = 8 waves. Wave w: k-tiles {2w, 2w+1} x 4 a-tiles.
// mfma_f32_16x16x32_bf16: A lane frag = A[row=l&15][k=8*(l>>4)+j] (8 contig),
// B lane frag = B[k=8*(l>>4)+j][col=l&15]; D: row=(l>>4)*4+r, col=l&15.
__global__ __launch_bounds__(512) void proj_mfma(
    const unsigned short* __restrict__ Ub, const unsigned short* __restrict__ Ib,
    const unsigned short* __restrict__ Wub, const unsigned short* __restrict__ Wib,
    unsigned short* __restrict__ WUU, unsigned short* __restrict__ WII)
{
    const int t = threadIdx.x;
    const int b = blockIdx.x, side = blockIdx.y;
    const unsigned short* W = side ? Wib : Wub;
    const unsigned short* X = (side ? Ib : Ub) + (size_t)b * NA * NH1;
    unsigned short* OUT = (side ? WII : WUU) + (size_t)b * NH2 * NA;
    const int w  = __builtin_amdgcn_readfirstlane(t >> 6);
    const int l  = t & 63;
    const int lr = l & 15;
    const int lk = (l >> 4) * 8;

    f32x4 acc[2][4];
    #pragma unroll
    for (int kt = 0; kt < 2; ++kt)
        #pragma unroll
        for (int at = 0; at < 4; ++at) acc[kt][at] = (f32x4)(0.f);

    #pragma unroll
    for (int h0 = 0; h0 < NH1; h0 += 32) {
        bf16x8 afr[2], bfr[4];
        #pragma unroll
        for (int kt = 0; kt < 2; ++kt)
            afr[kt] = *reinterpret_cast<const bf16x8*>(
                W + (size_t)((w * 2 + kt) * 16 + lr) * NH1 + h0 + lk);
        #pragma unroll
        for (int at = 0; at < 4; ++at)
            bfr[at] = *reinterpret_cast<const bf16x8*>(
                X + (size_t)(at * 16 + lr) * NH1 + h0 + lk);
        #pragma unroll
        for (int kt = 0; kt < 2; ++kt)
            #pragma unroll
            for (int at = 0; at < 4; ++at)
                acc[kt][at] = __builtin_amdgcn_mfma_f32_16x16x32_bf16(
                    afr[kt], bfr[at], acc[kt][at], 0, 0, 0);
    }

    #pragma unroll
    for (int kt = 0; kt < 2; ++kt) {
        const int kbase = (w * 2 + kt) * 16 + (l >> 4) * 4;
        #pragma unroll
        for (int at = 0; at < 4; ++at) {
            const int col = at * 16 + lr;
            #pragma unroll
            for (int r = 0; r < 4; ++r)
                OUT[(size_t)(kbase + r) * NA + col] = f2bf(acc[kt][at][r]);
        }
    }
}

// ---------------- K2: sim (f32 compute, bf16 SIM + SIMT outputs) -------------
// grid (B, 2 u-halves), 256 thr: tx=i-tile(4), ty=u-tile(2).
__global__ __launch_bounds__(256) void sim_kernel(
    const float* __restrict__ U, const float* __restrict__ I,
    unsigned short* __restrict__ SIM, unsigned short* __restrict__ SIMT)
{
    const int t = threadIdx.x;
    const int b = blockIdx.x, uh = blockIdx.y;
    const int tx = t & 15, ty = t >> 4;
    const int u0 = uh * 32 + ty * 2;
    const int i0 = tx * 4;
    const float4* U4 = reinterpret_cast<const float4*>(U + ((size_t)b * NA + u0) * NH1);
    const float4* I4 = reinterpret_cast<const float4*>(I + ((size_t)b * NA + i0) * NH1);

    float acc[2][4] = {};
    for (int h4 = 0; h4 < 64; ++h4) {
        float4 uv[2], iv[4];
        uv[0] = U4[h4];
        uv[1] = U4[64 + h4];
        #pragma unroll
        for (int d = 0; d < 4; ++d) iv[d] = I4[(size_t)d * 64 + h4];
        #pragma unroll
        for (int du = 0; du < 2; ++du)
            #pragma unroll
            for (int di = 0; di < 4; ++di)
                acc[du][di] += fabsf(uv[du].x - iv[di].x) + fabsf(uv[du].y - iv[di].y)
                             + fabsf(uv[du].z - iv[di].z) + fabsf(uv[du].w - iv[di].w);
    }
    float s[2][4];
    #pragma unroll
    for (int du = 0; du < 2; ++du)
        #pragma unroll
        for (int di = 0; di < 4; ++di) s[du][di] = 1.0f / (1.0f + acc[du][di]);

    unsigned short* SB = SIM  + (size_t)b * NA * NA;
    unsigned short* TB = SIMT + (size_t)b * NA * NA;
    #pragma unroll
    for (int du = 0; du < 2; ++du) {
        u16x4 v;
        #pragma unroll
        for (int di = 0; di < 4; ++di) v[di] = f2bf(s[du][di]);
        *reinterpret_cast<u16x4*>(SB + (size_t)(u0 + du) * NA + i0) = v;
    }
    #pragma unroll
    for (int di = 0; di < 4; ++di) {
        unsigned v = ((unsigned)f2bf(s[1][di]) << 16) | (unsigned)f2bf(s[0][di]);
        *reinterpret_cast<unsigned*>(TB + (size_t)(i0 + di) * NA + u0) = v;
    }
}

// ---------------- K3: score via MFMA + fused relu/<w,.>/softmax --------------
// side 0: score[u] = sum_k whu[k]*relu(WUU[k][u] + sum_i WII[k][i]*SIM[u][i])
// side 1: score[i] = sum_k whi[k]*relu(WII[k][i] + sum_u WUU[k][u]*SIMT[i][u])
// D[M=k=256][N=own=64], K=other=64. A = ROWS rows (contig over other);
// B^T rows = SM rows (side0: SIM[u][i], side1: SIMT[i][u]).
__global__ __launch_bounds__(512) void score_mfma(
    const unsigned short* __restrict__ WUU, const unsigned short* __restrict__ WII,
    const unsigned short* __restrict__ SIMB, const unsigned short* __restrict__ SIMTB,
    const float* __restrict__ whu, const float* __restrict__ whi,
    float* __restrict__ out)
{
    const int t = threadIdx.x;
    const int b = blockIdx.x, side = blockIdx.y;
    const unsigned short* A    = (side ? WUU : WII) + (size_t)b * NH2 * NA;
    const unsigned short* BIAS = (side ? WII : WUU) + (size_t)b * NH2 * NA;
    const unsigned short* SM   = (side ? SIMTB : SIMB) + (size_t)b * NA * NA;
    const float* wv = side ? whi : whu;
    const int w  = __builtin_amdgcn_readfirstlane(t >> 6);
    const int l  = t & 63;
    const int lr = l & 15;
    const int lk = (l >> 4) * 8;

    f32x4 acc[2][4];
    #pragma unroll
    for (int kt = 0; kt < 2; ++kt)
        #pragma unroll
        for (int ot = 0; ot < 4; ++ot) acc[kt][ot] = (f32x4)(0.f);

    #pragma unroll
    for (int kk = 0; kk < 64; kk += 32) {
        bf16x8 afr[2], bfr[4];
        #pragma unroll
        for (int kt = 0; kt < 2; ++kt)
            afr[kt] = *reinterpret_cast<const bf16x8*>(
                A + (size_t)((w * 2 + kt) * 16 + lr) * NA + kk + lk);
        #pragma unroll
        for (int ot = 0; ot < 4; ++ot)
            bfr[ot] = *reinterpret_cast<const bf16x8*>(
                SM + (size_t)(ot * 16 + lr) * NA + kk + lk);
        #pragma unroll
        for (int kt = 0; kt < 2; ++kt)
            #pragma unroll
            for (int ot = 0; ot < 4; ++ot)
                acc[kt][ot] = __builtin_amdgcn_mfma_f32_16x16x32_bf16(
                    afr[kt], bfr[ot], acc[kt][ot], 0, 0, 0);
    }

    float pot[4] = {0.f, 0.f, 0.f, 0.f};
    #pragma unroll
    for (int kt = 0; kt < 2; ++kt) {
        const int kbase = (w * 2 + kt) * 16 + (l >> 4) * 4;
        float wreg[4];
        #pragma unroll
        for (int r = 0; r < 4; ++r) wreg[r] = wv[kbase + r];
        #pragma unroll
        for (int ot = 0; ot < 4; ++ot) {
            const int col = ot * 16 + lr;
            float p = 0.f;
            #pragma unroll
            for (int r = 0; r < 4; ++r) {
                float h = acc[kt][ot][r] + bf2f(BIAS[(size_t)(kbase + r) * NA + col]);
                h = fmaxf(h, 0.f);
                p = fmaf(wreg[r], h, p);
            }
            pot[ot] += p;
        }
    }
    #pragma unroll
    for (int ot = 0; ot < 4; ++ot) {
        pot[ot] += __shfl_xor(pot[ot], 16, 64);
        pot[ot] += __shfl_xor(pot[ot], 32, 64);
    }
    __shared__ float red[8][64];
    if (l < 16) {
        #pragma unroll
        for (int ot = 0; ot < 4; ++ot) red[w][ot * 16 + l] = pot[ot];
    }
    __syncthreads();
    if (t < 64) {
        float sc = 0.f;
        #pragma unroll
        for (int q = 0; q < 8; ++q) sc += red[q][t];
        float m = sc;
        #pragma unroll
        for (int off = 32; off >= 1; off >>= 1) m = fmaxf(m, __shfl_xor(m, off, 64));
        float e = __expf(sc - m);
        float ssum = e;
        #pragma unroll
        for (int off = 32; off >= 1; off >>= 1) ssum += __shfl_xor(ssum, off, 64);
        out[(size_t)side * (NB * NA) + (size_t)b * NA + t] = e / ssum;
    }
}

extern "C" void kernel_launch(void* const* d_in, const int* in_sizes, int n_in,
                              void* d_out, int out_size, void* d_ws, size_t ws_size,
                              hipStream_t stream)
{
    const float* U   = (const float*)d_in[0];
    const float* I   = (const float*)d_in[1];
    const float* Wu  = (const float*)d_in[2];
    const float* Wi  = (const float*)d_in[3];
    const float* whu = (const float*)d_in[4];
    const float* whi = (const float*)d_in[5];
    float* out = (float*)d_out;

    char* ws = (char*)d_ws;
    unsigned short* Ub    = (unsigned short*)(ws);             // 4,194,304 B
    unsigned short* Ib    = (unsigned short*)(ws + 4194304);   // 4,194,304 B
    unsigned short* Wub   = (unsigned short*)(ws + 8388608);   //   131,072 B
    unsigned short* Wib   = (unsigned short*)(ws + 8519680);   //   131,072 B
    unsigned short* WUU   = (unsigned short*)(ws + 8650752);   // 4,194,304 B
    unsigned short* WII   = (unsigned short*)(ws + 12845056);  // 4,194,304 B
    unsigned short* SIMb  = (unsigned short*)(ws + 17039360);  // 1,048,576 B
    unsigned short* SIMTb = (unsigned short*)(ws + 18087936);  // 1,048,576 B

    cvt_kernel<<<2112, 256, 0, stream>>>(U, I, Wu, Wi, Ub, Ib, Wub, Wib);
    sim_kernel<<<dim3(NB, 2), 256, 0, stream>>>(U, I, SIMb, SIMTb);
    proj_mfma<<<dim3(NB, 2), 512, 0, stream>>>(Ub, Ib, Wub, Wib, WUU, WII);
    score_mfma<<<dim3(NB, 2), 512, 0, stream>>>(WUU, WII, SIMb, SIMTb, whu, whi, out);
}

// Round 3
// 104.589 us; speedup vs baseline: 1.9379x; 1.2277x over previous
//
#include <hip/hip_runtime.h>

#define NB 128
#define NA 64
#define NH1 256
#define NH2 256

typedef __attribute__((ext_vector_type(8))) short bf16x8;
typedef __attribute__((ext_vector_type(4))) float f32x4;
typedef __attribute__((ext_vector_type(8))) unsigned short u16x8;
typedef __attribute__((ext_vector_type(4))) unsigned short u16x4;

__device__ __forceinline__ unsigned short f2bf(float f) {
    union { float f; unsigned u; } v; v.f = f;
    unsigned r = v.u + 0x7FFFu + ((v.u >> 16) & 1u);   // RNE, inputs finite
    return (unsigned short)(r >> 16);
}

// ---------------- K0: convert W_u, W_i to bf16 (131072 elems) ----------------
__global__ __launch_bounds__(256) void cvt_w(
    const float* __restrict__ Wu, const float* __restrict__ Wi,
    unsigned short* __restrict__ Wub, unsigned short* __restrict__ Wib)
{
    const size_t e = ((size_t)blockIdx.x * 256 + threadIdx.x) * 8;
    const float* src; unsigned short* dst; size_t off;
    if (e < 65536) { src = Wu; dst = Wub; off = e; }
    else           { src = Wi; dst = Wib; off = e - 65536; }
    float4 a = *reinterpret_cast<const float4*>(src + off);
    float4 b = *reinterpret_cast<const float4*>(src + off + 4);
    u16x8 o;
    o[0] = f2bf(a.x); o[1] = f2bf(a.y); o[2] = f2bf(a.z); o[3] = f2bf(a.w);
    o[4] = f2bf(b.x); o[5] = f2bf(b.y); o[6] = f2bf(b.z); o[7] = f2bf(b.w);
    *reinterpret_cast<u16x8*>(dst + off) = o;
}

// ---------------- K1: sim, LDS-staged f32, interleaved tiles -----------------
// grid (B, 2 u-halves), 256 thr. Thread (tx,ty): u in {32uh+ty, +16}, i in {tx+16di}.
#define SPAD 260   // f32 row stride (1040 B, 16B-aligned; 260 % 32 == 4 -> <=2-way)
__global__ __launch_bounds__(256) void sim_kernel(
    const float* __restrict__ U, const float* __restrict__ I,
    unsigned short* __restrict__ SIM, unsigned short* __restrict__ SIMT)
{
    __shared__ float Ush[32 * SPAD];
    __shared__ float Ish[64 * SPAD];
    const int t = threadIdx.x, b = blockIdx.x, uh = blockIdx.y;

    const float4* Ug = reinterpret_cast<const float4*>(U + ((size_t)b * NA + uh * 32) * NH1);
    const float4* Ig = reinterpret_cast<const float4*>(I + (size_t)b * NA * NH1);
    #pragma unroll
    for (int k = 0; k < 24; ++k) {          // (32+64) rows * 64 f4 = 6144 f4
        const int g = t + k * 256;
        if (k < 8) {                        // g < 2048: U half
            float4 v = Ug[g];
            *reinterpret_cast<float4*>(&Ush[(g >> 6) * SPAD + (g & 63) * 4]) = v;
        } else {
            const int g2 = g - 2048;
            float4 v = Ig[g2];
            *reinterpret_cast<float4*>(&Ish[(g2 >> 6) * SPAD + (g2 & 63) * 4]) = v;
        }
    }
    __syncthreads();

    const int tx = t & 15, ty = t >> 4;
    float acc[2][4] = {};
    #pragma unroll 4
    for (int h4 = 0; h4 < 64; ++h4) {
        float4 uv[2], iv[4];
        uv[0] = *reinterpret_cast<const float4*>(&Ush[ty * SPAD + h4 * 4]);
        uv[1] = *reinterpret_cast<const float4*>(&Ush[(ty + 16) * SPAD + h4 * 4]);
        #pragma unroll
        for (int di = 0; di < 4; ++di)
            iv[di] = *reinterpret_cast<const float4*>(&Ish[(tx + di * 16) * SPAD + h4 * 4]);
        #pragma unroll
        for (int du = 0; du < 2; ++du)
            #pragma unroll
            for (int di = 0; di < 4; ++di)
                acc[du][di] += fabsf(uv[du].x - iv[di].x) + fabsf(uv[du].y - iv[di].y)
                             + fabsf(uv[du].z - iv[di].z) + fabsf(uv[du].w - iv[di].w);
    }

    unsigned short* SB = SIM  + (size_t)b * NA * NA;
    unsigned short* TB = SIMT + (size_t)b * NA * NA;
    #pragma unroll
    for (int du = 0; du < 2; ++du) {
        const int u = uh * 32 + ty + du * 16;
        #pragma unroll
        for (int di = 0; di < 4; ++di) {
            const int i = tx + di * 16;
            const unsigned short sv = f2bf(1.0f / (1.0f + acc[du][di]));
            SB[(size_t)u * NA + i] = sv;
            TB[(size_t)i * NA + u] = sv;
        }
    }
}

// ---------------- K2: fused proj(MFMA) + score(MFMA) + softmax ---------------
// grid 128 (=b), 1024 thr = 16 waves. Wave w: side s=w>>3, k-slice wk=w&7 (32 rows).
// Phase A: WUU/WII[k][a] = sum_h W[k][h]*X[a][h]; acc regs kept as f32 bias.
// Phase B: score side s: A = P[s^1] (LDS), B = SM rows (global bf16), bias = acc.
#define XPAD 264   // bf16 row stride (528 B, 16B-aligned)
#define PPAD 72    // bf16 row stride (144 B, 16B-aligned)
__global__ __launch_bounds__(1024) void fused_kernel(
    const float* __restrict__ U, const float* __restrict__ I,
    const unsigned short* __restrict__ Wub, const unsigned short* __restrict__ Wib,
    const unsigned short* __restrict__ SIM, const unsigned short* __restrict__ SIMT,
    const float* __restrict__ whu, const float* __restrict__ whi,
    float* __restrict__ out)
{
    __shared__ unsigned short Xl[2][64 * XPAD];   // 67,584 B
    __shared__ unsigned short Pl[2][256 * PPAD];  // 73,728 B
    __shared__ float red[16 * 64];                //  4,096 B
    const int t = threadIdx.x, b = blockIdx.x;

    // ---- stage X (both sides) f32 -> bf16 LDS: 8192 f4 / 1024 thr = 8 each
    #pragma unroll
    for (int k = 0; k < 8; ++k) {
        const int g = t + k * 1024;
        const int side = g >> 12;
        const int rem = g & 4095;
        const float* X = side ? I : U;
        float4 v = *reinterpret_cast<const float4*>(
            X + ((size_t)b * NA + (rem >> 6)) * NH1 + (rem & 63) * 4);
        u16x4 o;
        o[0] = f2bf(v.x); o[1] = f2bf(v.y); o[2] = f2bf(v.z); o[3] = f2bf(v.w);
        *reinterpret_cast<u16x4*>(&Xl[side][(rem >> 6) * XPAD + (rem & 63) * 4]) = o;
    }
    __syncthreads();

    const int w  = __builtin_amdgcn_readfirstlane(t >> 6);
    const int l  = t & 63;
    const int lr = l & 15;
    const int lk = (l >> 4) * 8;
    const int s  = w >> 3;       // proj/score side of this wave
    const int wk = w & 7;        // 32-row k-slice

    const unsigned short* Wb = s ? Wib : Wub;
    f32x4 acc[2][4];
    #pragma unroll
    for (int kt = 0; kt < 2; ++kt)
        #pragma unroll
        for (int at = 0; at < 4; ++at) acc[kt][at] = (f32x4)(0.f);

    // ---- phase A: projection MFMAs (A = W global bf16, B = X LDS)
    #pragma unroll
    for (int h0 = 0; h0 < NH1; h0 += 32) {
        bf16x8 afr[2], bfr[4];
        #pragma unroll
        for (int kt = 0; kt < 2; ++kt)
            afr[kt] = *reinterpret_cast<const bf16x8*>(
                Wb + (size_t)(wk * 32 + kt * 16 + lr) * NH1 + h0 + lk);
        #pragma unroll
        for (int at = 0; at < 4; ++at)
            bfr[at] = *reinterpret_cast<const bf16x8*>(
                &Xl[s][(at * 16 + lr) * XPAD + h0 + lk]);
        #pragma unroll
        for (int kt = 0; kt < 2; ++kt)
            #pragma unroll
            for (int at = 0; at < 4; ++at)
                acc[kt][at] = __builtin_amdgcn_mfma_f32_16x16x32_bf16(
                    afr[kt], bfr[at], acc[kt][at], 0, 0, 0);
    }

    // ---- write P[s] = proj result (bf16) for the other side's contraction
    #pragma unroll
    for (int kt = 0; kt < 2; ++kt) {
        const int kb = wk * 32 + kt * 16 + (l >> 4) * 4;
        #pragma unroll
        for (int at = 0; at < 4; ++at)
            #pragma unroll
            for (int r = 0; r < 4; ++r)
                Pl[s][(kb + r) * PPAD + at * 16 + lr] = f2bf(acc[kt][at][r]);
    }
    __syncthreads();

    // ---- phase B: score contraction + relu + <w,.>
    const unsigned short* SMg = (s ? SIMT : SIM) + (size_t)b * NA * NA;
    const unsigned short* Alds = Pl[s ^ 1];
    const float* wv = s ? whi : whu;

    float partial[4] = {0.f, 0.f, 0.f, 0.f};
    #pragma unroll
    for (int kt = 0; kt < 2; ++kt) {
        f32x4 sacc[4];
        #pragma unroll
        for (int ot = 0; ot < 4; ++ot) sacc[ot] = (f32x4)(0.f);
        #pragma unroll
        for (int kk = 0; kk < NA; kk += 32) {
            bf16x8 af = *reinterpret_cast<const bf16x8*>(
                &Alds[(wk * 32 + kt * 16 + lr) * PPAD + kk + lk]);
            #pragma unroll
            for (int ot = 0; ot < 4; ++ot) {
                bf16x8 bf = *reinterpret_cast<const bf16x8*>(
                    SMg + (size_t)(ot * 16 + lr) * NA + kk + lk);
                sacc[ot] = __builtin_amdgcn_mfma_f32_16x16x32_bf16(af, bf, sacc[ot], 0, 0, 0);
            }
        }
        const int kb = wk * 32 + kt * 16 + (l >> 4) * 4;
        float wreg[4];
        #pragma unroll
        for (int r = 0; r < 4; ++r) wreg[r] = wv[kb + r];
        #pragma unroll
        for (int ot = 0; ot < 4; ++ot) {
            float p = 0.f;
            #pragma unroll
            for (int r = 0; r < 4; ++r) {
                float h = acc[kt][ot][r] + sacc[ot][r];   // f32 bias from regs
                h = fmaxf(h, 0.f);
                p = fmaf(wreg[r], h, p);
            }
            partial[ot] += p;
        }
    }
    #pragma unroll
    for (int ot = 0; ot < 4; ++ot) {
        partial[ot] += __shfl_xor(partial[ot], 16, 64);
        partial[ot] += __shfl_xor(partial[ot], 32, 64);
    }
    if (l < 16) {
        #pragma unroll
        for (int ot = 0; ot < 4; ++ot) red[w * 64 + ot * 16 + l] = partial[ot];
    }
    __syncthreads();

    // ---- softmax (wave 0: user, wave 1: item)
    if (t < 128) {
        const int side = t >> 6, own = t & 63;
        float sc = 0.f;
        #pragma unroll
        for (int q = 0; q < 8; ++q) sc += red[(side * 8 + q) * 64 + own];
        float m = sc;
        #pragma unroll
        for (int off = 32; off >= 1; off >>= 1) m = fmaxf(m, __shfl_xor(m, off, 64));
        float e = __expf(sc - m);
        float ssum = e;
        #pragma unroll
        for (int off = 32; off >= 1; off >>= 1) ssum += __shfl_xor(ssum, off, 64);
        out[(size_t)side * (NB * NA) + (size_t)b * NA + own] = e / ssum;
    }
}

extern "C" void kernel_launch(void* const* d_in, const int* in_sizes, int n_in,
                              void* d_out, int out_size, void* d_ws, size_t ws_size,
                              hipStream_t stream)
{
    const float* U   = (const float*)d_in[0];
    const float* I   = (const float*)d_in[1];
    const float* Wu  = (const float*)d_in[2];
    const float* Wi  = (const float*)d_in[3];
    const float* whu = (const float*)d_in[4];
    const float* whi = (const float*)d_in[5];
    float* out = (float*)d_out;

    char* ws = (char*)d_ws;
    unsigned short* Wub  = (unsigned short*)(ws);             // 131,072 B
    unsigned short* Wib  = (unsigned short*)(ws + 131072);    // 131,072 B
    unsigned short* SIMb = (unsigned short*)(ws + 262144);    // 1,048,576 B
    unsigned short* SIMTb= (unsigned short*)(ws + 1310720);   // 1,048,576 B

    cvt_w<<<64, 256, 0, stream>>>(Wu, Wi, Wub, Wib);
    sim_kernel<<<dim3(NB, 2), 256, 0, stream>>>(U, I, SIMb, SIMTb);
    fused_kernel<<<NB, 1024, 0, stream>>>(U, I, Wub, Wib, SIMb, SIMTb, whu, whi, out);
}

// Round 4
// 94.960 us; speedup vs baseline: 2.1344x; 1.1014x over previous
//
#include <hip/hip_runtime.h>

#define NB 128
#define NA 64
#define NH1 256
#define NH2 256

typedef __attribute__((ext_vector_type(8))) short bf16x8;
typedef __attribute__((ext_vector_type(4))) float f32x4;
typedef __attribute__((ext_vector_type(8))) unsigned short u16x8;
typedef __attribute__((ext_vector_type(4))) unsigned short u16x4;
typedef _Float16 f16x2 __attribute__((ext_vector_type(2)));

__device__ __forceinline__ unsigned short f2bf(float f) {
    union { float f; unsigned u; } v; v.f = f;
    unsigned r = v.u + 0x7FFFu + ((v.u >> 16) & 1u);   // RNE, inputs finite
    return (unsigned short)(r >> 16);
}
__device__ __forceinline__ f16x2 habs2(f16x2 x) {
    union { f16x2 h; unsigned u; } v; v.h = x; v.u &= 0x7FFF7FFFu; return v.h;
}

// XOR swizzle: permute 16B slots within a 128B window by row (T2)
#define XSWZ(row, cb) ((cb) ^ (((row) & 7) << 4))

// ---------------- K0: convert W_u, W_i to bf16 (131072 elems) ----------------
__global__ __launch_bounds__(256) void cvt_w(
    const float* __restrict__ Wu, const float* __restrict__ Wi,
    unsigned short* __restrict__ Wub, unsigned short* __restrict__ Wib)
{
    const size_t e = ((size_t)blockIdx.x * 256 + threadIdx.x) * 8;
    const float* src; unsigned short* dst; size_t off;
    if (e < 65536) { src = Wu; dst = Wub; off = e; }
    else           { src = Wi; dst = Wib; off = e - 65536; }
    float4 a = *reinterpret_cast<const float4*>(src + off);
    float4 b = *reinterpret_cast<const float4*>(src + off + 4);
    u16x8 o;
    o[0] = f2bf(a.x); o[1] = f2bf(a.y); o[2] = f2bf(a.z); o[3] = f2bf(a.w);
    o[4] = f2bf(b.x); o[5] = f2bf(b.y); o[6] = f2bf(b.z); o[7] = f2bf(b.w);
    *reinterpret_cast<u16x8*>(dst + off) = o;
}

// ---------------- K1: sim via packed fp16, LDS-staged ------------------------
// grid (B, 2 u-halves), 512 thr. Thread (tx,ty): u = uh*32+ty, i = tx+16*di.
#define SROW 264   // halfs per row: 528 B (16B-aligned), 132 dwords % 32 == 4
__global__ __launch_bounds__(512) void sim_kernel(
    const float* __restrict__ U, const float* __restrict__ I,
    unsigned short* __restrict__ SIM, unsigned short* __restrict__ SIMT)
{
    __shared__ __align__(16) _Float16 sh[96 * SROW];   // 50,688 B
    const int t = threadIdx.x, b = blockIdx.x, uh = blockIdx.y;

    const float4* Ug = reinterpret_cast<const float4*>(U + ((size_t)b * NA + uh * 32) * NH1);
    const float4* Ig = reinterpret_cast<const float4*>(I + (size_t)b * NA * NH1);
    #pragma unroll
    for (int it = 0; it < 12; ++it) {          // 96 rows * 64 f4 = 6144 f4
        const int g = t + it * 512;
        float4 v = (g < 2048) ? Ug[g] : Ig[g - 2048];
        const int row = g >> 6, c4 = g & 63;
        f16x2 h0; h0.x = (_Float16)v.x; h0.y = (_Float16)v.y;
        f16x2 h1; h1.x = (_Float16)v.z; h1.y = (_Float16)v.w;
        union { f16x2 h[2]; float2 f; } pk; pk.h[0] = h0; pk.h[1] = h1;
        *reinterpret_cast<float2*>(&sh[row * SROW + c4 * 4]) = pk.f;
    }
    __syncthreads();

    const int tx = t & 15, ty = t >> 4;        // ty 0..31
    f16x2 acc[4];
    #pragma unroll
    for (int di = 0; di < 4; ++di) { acc[di].x = (_Float16)0; acc[di].y = (_Float16)0; }

    const _Float16* Urow = &sh[ty * SROW];
    #pragma unroll 4
    for (int h8 = 0; h8 < 32; ++h8) {          // 8 halfs (16B) per step
        union { float4 f; f16x2 h[4]; } uv, iv;
        uv.f = *reinterpret_cast<const float4*>(&Urow[h8 * 8]);
        #pragma unroll
        for (int di = 0; di < 4; ++di) {
            iv.f = *reinterpret_cast<const float4*>(&sh[(32 + tx + di * 16) * SROW + h8 * 8]);
            #pragma unroll
            for (int c = 0; c < 4; ++c)
                acc[di] = acc[di] + habs2(uv.h[c] - iv.h[c]);
        }
    }

    const int u = uh * 32 + ty;
    unsigned short* SB = SIM  + (size_t)b * NA * NA;
    unsigned short* TB = SIMT + (size_t)b * NA * NA;
    #pragma unroll
    for (int di = 0; di < 4; ++di) {
        const int i = tx + di * 16;
        const float sum = (float)acc[di].x + (float)acc[di].y;
        const unsigned short sv = f2bf(1.0f / (1.0f + sum));
        SB[(size_t)u * NA + i] = sv;
        TB[(size_t)i * NA + u] = sv;
    }
}

// ---------------- K2: fused dual-proj(MFMA) + score(MFMA) + softmax ----------
// grid (B, side), 512 thr = 8 waves. Wave w owns 32 k-rows.
// Computes BOTH projections: own side kept in regs (f32 bias), other side ->
// Pl (bf16 LDS, swizzled) as the score contraction's A operand.
__global__ __launch_bounds__(512) void fused_kernel(
    const float* __restrict__ U, const float* __restrict__ I,
    const unsigned short* __restrict__ Wub, const unsigned short* __restrict__ Wib,
    const unsigned short* __restrict__ SIM, const unsigned short* __restrict__ SIMT,
    const float* __restrict__ whu, const float* __restrict__ whi,
    float* __restrict__ out)
{
    __shared__ __align__(16) unsigned short Xl[2 * 64 * 256];  // 65,536 B, 512B rows, swz
    __shared__ __align__(16) unsigned short Pl[256 * 64];      // 32,768 B, 128B rows, swz
    __shared__ float red[8 * 64];                              //  2,048 B
    const int t = threadIdx.x, b = blockIdx.x, s = blockIdx.y;

    // ---- stage X both sides f32 -> bf16 LDS (swizzled): 8192 f4 / 512 thr
    #pragma unroll
    for (int it = 0; it < 16; ++it) {
        const int g = t + it * 512;
        const int side = g >> 12, rem = g & 4095;
        const int row = rem >> 6, c4 = rem & 63;
        const float* X = side ? I : U;
        float4 v = *reinterpret_cast<const float4*>(X + ((size_t)b * NA + row) * NH1 + c4 * 4);
        u16x4 o;
        o[0] = f2bf(v.x); o[1] = f2bf(v.y); o[2] = f2bf(v.z); o[3] = f2bf(v.w);
        char* dst = (char*)Xl + side * 32768 + row * 512 + XSWZ(row, c4 * 8);
        *reinterpret_cast<u16x4*>(dst) = o;
    }
    __syncthreads();

    const int w  = __builtin_amdgcn_readfirstlane(t >> 6);  // 0..7
    const int l  = t & 63;
    const int lr = l & 15;
    const int lk = (l >> 4) * 8;

    const unsigned short* Ws = s ? Wib : Wub;   // own-side weights
    const unsigned short* Wo = s ? Wub : Wib;   // other-side weights

    f32x4 accO[2][4], accX[2][4];
    #pragma unroll
    for (int kt = 0; kt < 2; ++kt)
        #pragma unroll
        for (int at = 0; at < 4; ++at) { accO[kt][at] = (f32x4)(0.f); accX[kt][at] = (f32x4)(0.f); }

    // ---- dual projection
    #pragma unroll
    for (int h0 = 0; h0 < NH1; h0 += 32) {
        bf16x8 as_[2], ao_[2], bs_[4], bo_[4];
        #pragma unroll
        for (int kt = 0; kt < 2; ++kt) {
            const size_t roff = (size_t)(w * 32 + kt * 16 + lr) * NH1 + h0 + lk;
            as_[kt] = *reinterpret_cast<const bf16x8*>(Ws + roff);
            ao_[kt] = *reinterpret_cast<const bf16x8*>(Wo + roff);
        }
        #pragma unroll
        for (int at = 0; at < 4; ++at) {
            const int row = at * 16 + lr;
            const int cb  = XSWZ(row, (h0 + lk) * 2);
            bs_[at] = *reinterpret_cast<const bf16x8*>((char*)Xl + s * 32768 + row * 512 + cb);
            bo_[at] = *reinterpret_cast<const bf16x8*>((char*)Xl + (s ^ 1) * 32768 + row * 512 + cb);
        }
        #pragma unroll
        for (int kt = 0; kt < 2; ++kt)
            #pragma unroll
            for (int at = 0; at < 4; ++at) {
                accO[kt][at] = __builtin_amdgcn_mfma_f32_16x16x32_bf16(as_[kt], bs_[at], accO[kt][at], 0, 0, 0);
                accX[kt][at] = __builtin_amdgcn_mfma_f32_16x16x32_bf16(ao_[kt], bo_[at], accX[kt][at], 0, 0, 0);
            }
    }

    // ---- write other-side projection to Pl (bf16, swizzled)
    #pragma unroll
    for (int kt = 0; kt < 2; ++kt) {
        const int kb = w * 32 + kt * 16 + (l >> 4) * 4;
        #pragma unroll
        for (int at = 0; at < 4; ++at)
            #pragma unroll
            for (int r = 0; r < 4; ++r) {
                const int row = kb + r;
                *reinterpret_cast<unsigned short*>(
                    (char*)Pl + row * 128 + XSWZ(row, (at * 16 + lr) * 2)) = f2bf(accX[kt][at][r]);
            }
    }
    __syncthreads();

    // ---- score contraction: D[k][own] = sum_other Pl[k][other] * SM[own][other]
    const unsigned short* SMg = (s ? SIMT : SIM) + (size_t)b * NA * NA;
    const float* wv = s ? whi : whu;

    bf16x8 bfr2[2][4];
    #pragma unroll
    for (int kk2 = 0; kk2 < 2; ++kk2)
        #pragma unroll
        for (int ot = 0; ot < 4; ++ot)
            bfr2[kk2][ot] = *reinterpret_cast<const bf16x8*>(
                SMg + (size_t)(ot * 16 + lr) * NA + kk2 * 32 + lk);

    float partial[4] = {0.f, 0.f, 0.f, 0.f};
    #pragma unroll
    for (int kt = 0; kt < 2; ++kt) {
        f32x4 sacc[4];
        #pragma unroll
        for (int ot = 0; ot < 4; ++ot) sacc[ot] = (f32x4)(0.f);
        #pragma unroll
        for (int kk2 = 0; kk2 < 2; ++kk2) {
            const int arow = w * 32 + kt * 16 + lr;
            bf16x8 af = *reinterpret_cast<const bf16x8*>(
                (char*)Pl + arow * 128 + XSWZ(arow, (kk2 * 32 + lk) * 2));
            #pragma unroll
            for (int ot = 0; ot < 4; ++ot)
                sacc[ot] = __builtin_amdgcn_mfma_f32_16x16x32_bf16(af, bfr2[kk2][ot], sacc[ot], 0, 0, 0);
        }
        const int kb = w * 32 + kt * 16 + (l >> 4) * 4;
        float wr[4];
        #pragma unroll
        for (int r = 0; r < 4; ++r) wr[r] = wv[kb + r];
        #pragma unroll
        for (int ot = 0; ot < 4; ++ot) {
            float p = 0.f;
            #pragma unroll
            for (int r = 0; r < 4; ++r) {
                float h = accO[kt][ot][r] + sacc[ot][r];   // f32 bias from regs
                h = fmaxf(h, 0.f);
                p = fmaf(wr[r], h, p);
            }
            partial[ot] += p;
        }
    }
    #pragma unroll
    for (int ot = 0; ot < 4; ++ot) {
        partial[ot] += __shfl_xor(partial[ot], 16, 64);
        partial[ot] += __shfl_xor(partial[ot], 32, 64);
    }
    if (l < 16) {
        #pragma unroll
        for (int ot = 0; ot < 4; ++ot) red[w * 64 + ot * 16 + l] = partial[ot];
    }
    __syncthreads();

    if (t < 64) {
        float sc = 0.f;
        #pragma unroll
        for (int q = 0; q < 8; ++q) sc += red[q * 64 + t];
        float m = sc;
        #pragma unroll
        for (int off = 32; off >= 1; off >>= 1) m = fmaxf(m, __shfl_xor(m, off, 64));
        float e = __expf(sc - m);
        float ssum = e;
        #pragma unroll
        for (int off = 32; off >= 1; off >>= 1) ssum += __shfl_xor(ssum, off, 64);
        out[(size_t)s * (NB * NA) + (size_t)b * NA + t] = e / ssum;
    }
}

extern "C" void kernel_launch(void* const* d_in, const int* in_sizes, int n_in,
                              void* d_out, int out_size, void* d_ws, size_t ws_size,
                              hipStream_t stream)
{
    (void)in_sizes; (void)n_in; (void)out_size; (void)ws_size;
    const float* U   = (const float*)d_in[0];
    const float* I   = (const float*)d_in[1];
    const float* Wu  = (const float*)d_in[2];
    const float* Wi  = (const float*)d_in[3];
    const float* whu = (const float*)d_in[4];
    const float* whi = (const float*)d_in[5];
    float* out = (float*)d_out;

    char* ws = (char*)d_ws;
    unsigned short* Wub   = (unsigned short*)(ws);             // 131,072 B
    unsigned short* Wib   = (unsigned short*)(ws + 131072);    // 131,072 B
    unsigned short* SIMb  = (unsigned short*)(ws + 262144);    // 1,048,576 B
    unsigned short* SIMTb = (unsigned short*)(ws + 1310720);   // 1,048,576 B

    cvt_w<<<64, 256, 0, stream>>>(Wu, Wi, Wub, Wib);
    sim_kernel<<<dim3(NB, 2), 512, 0, stream>>>(U, I, SIMb, SIMTb);
    fused_kernel<<<dim3(NB, 2), 512, 0, stream>>>(U, I, Wub, Wib, SIMb, SIMTb, whu, whi, out);
}